// Round 2
// baseline (1446.183 us; speedup 1.0000x reference)
//
#include <hip/hip_runtime.h>
#include <cstdint>
#include <cmath>

// Problem constants (fixed by reference):
//   B=64 examples, D=128 dim, NP=512 nodes/tokens per example, 100 Jacobi Sinkhorn iters.
#define NB_EX 64
#define DIMD 128
#define NP 512
#define NITER 100
constexpr float MARG = 1.0f / 512.0f;   // a = b = 1/n

// ---------- helpers ----------
__device__ __forceinline__ float bf2f_lo(unsigned w) { return __uint_as_float(w << 16); }
__device__ __forceinline__ float bf2f_hi(unsigned w) { return __uint_as_float(w & 0xFFFF0000u); }
__device__ __forceinline__ unsigned short f2bf(float f) {
    unsigned u = __float_as_uint(f);
    u += 0x7FFFu + ((u >> 16) & 1u);      // RTNE
    return (unsigned short)(u >> 16);
}
__device__ __forceinline__ float wred64(float v) {
#pragma unroll
    for (int m = 1; m < 64; m <<= 1) v += __shfl_xor(v, m, 64);
    return v;
}

// ---------- workspace layout (bytes) ----------
// 0        : flag (int)  dtype detector result
// 256      : simg     64*64 f32 logits (16384)
// 16640    : rn_sg    64 f32
// 16896    : rn_qg    64 f32
// 17152    : rn_an    32768 f32 (131072)
// 148224   : rn_bn    32768 f32 (131072)
// 279296   : rowsum   64*512 f32 raw row sums (131072)
// 410368   : colpart  2 banks x 64*8*512 f32 (2097152)
// 2621440  : P0       64*512*512 bf16 (33554432)   -> total ~36.2 MB
#define O_SIMG   256
#define O_RNSG   16640
#define O_RNQG   16896
#define O_RNAN   17152
#define O_RNBN   148224
#define O_ROWSUM 279296
#define O_COLP   410368
#define O_P0     2621440
#define COLP_BANK (64 * 8 * 512)  // floats per bank

// ---------- dtype detector + output zero-init ----------
// bf16-pair low halfword exponent clusters in [110,130]; fp32 mantissa bits ~8% hit rate.
__global__ void k_detect(const unsigned* in0, int* flag, float* outf) {
    __shared__ int cnt;
    if (threadIdx.x == 0) cnt = 0;
    __syncthreads();
    unsigned w = in0[threadIdx.x];          // first 1KB; buffer >= 16 KB either way
    unsigned e = (w >> 7) & 0xFFu;          // exponent field of low bf16 (if bf16)
    if (e >= 110u && e <= 130u) atomicAdd(&cnt, 1);
    __syncthreads();
    if (threadIdx.x == 0) *flag = (cnt >= 128) ? 1 : 0;
    if (threadIdx.x < 3) outf[threadIdx.x] = 0.0f;   // d_out re-poisoned before every call
}

// ---------- inverse L2 norms per row (128-dim rows), one wave per row ----------
__global__ void k_rnorm(const void* in, float* rn, int rows, const int* flagp) {
    int flag = *flagp;
    int row  = blockIdx.x * 4 + (threadIdx.x >> 6);
    int lane = threadIdx.x & 63;
    if (row >= rows) return;
    float f0, f1;
    if (flag) {
        unsigned w = ((const unsigned*)in)[row * 64 + lane];
        f0 = bf2f_lo(w); f1 = bf2f_hi(w);
    } else {
        float2 v = ((const float2*)in)[row * 64 + lane];
        f0 = v.x; f1 = v.y;
    }
    float ss = wred64(f0 * f0 + f1 * f1);
    if (lane == 0) rn[row] = 1.0f / fmaxf(sqrtf(ss), 1e-12f);
}

// ---------- global sim logits: simg[i][j] = (s_i . q_j) * rn_i * rn_j / TEMP ----------
__global__ void k_simg(const void* sgr, const void* qgr, const float* rnsg, const float* rnqg,
                       float* simg, const int* flagp) {
    int flag = *flagp;
    int g = blockIdx.x * 256 + threadIdx.x;     // 4096 = 64*64
    int i = g >> 6, j = g & 63;
    float dot = 0.f;
    if (flag) {
        const unsigned* a = (const unsigned*)sgr + i * 64;
        const unsigned* b = (const unsigned*)qgr + j * 64;
        for (int k = 0; k < 64; k++) {
            unsigned wa = a[k], wb = b[k];
            dot += bf2f_lo(wa) * bf2f_lo(wb);
            dot += bf2f_hi(wa) * bf2f_hi(wb);
        }
    } else {
        const float4* a = (const float4*)sgr + i * 32;
        const float4* b = (const float4*)qgr + j * 32;
        for (int k = 0; k < 32; k++) {
            float4 x = a[k], y = b[k];
            dot += x.x * y.x + x.y * y.y + x.z * y.z + x.w * y.w;
        }
    }
    simg[g] = dot * rnsg[i] * rnqg[j] * 10.0f;   // /TEMP = *10
}

// ---------- global NT-Xent from sim logits; writes outf[0] and adds to outf[2] ----------
__global__ void k_gloss(const float* __restrict__ simg, float* outf) {
    __shared__ float red[64];
    int i = threadIdx.x;                        // 256 threads; first 64 active for compute
    if (i < 64) {
        float m = -1e30f;
        for (int j = 0; j < 64; j++) m = fmaxf(m, simg[i * 64 + j]);
        float se = 0.f;
        for (int j = 0; j < 64; j++) se += expf(simg[i * 64 + j] - m);
        float rl = simg[i * 64 + i] - (m + logf(se));
        float m2 = -1e30f;
        for (int j = 0; j < 64; j++) m2 = fmaxf(m2, simg[j * 64 + i]);
        float se2 = 0.f;
        for (int j = 0; j < 64; j++) se2 += expf(simg[j * 64 + i] - m2);
        float cl = simg[i * 64 + i] - (m2 + logf(se2));
        red[i] = rl + cl;
    }
    __syncthreads();
    if (i == 0) {
        float s = 0.f;
        for (int k = 0; k < 64; k++) s += red[k];
        float g = -s / 128.0f;                  // ((−Σrl/64)+(−Σcl/64))/2
        atomicAdd(&outf[0], g);
        atomicAdd(&outf[2], g);
    }
}

// ---------- build P0 = exp(10*sim) bf16, per-example 512x512, 128x128 tiles ----------
__global__ void k_build(const void* anr, const void* bnr, const float* rnan, const float* rnbn,
                        unsigned short* p0, const int* flagp) {
    int flag = *flagp;
    int b   = blockIdx.y;
    int r0t = (blockIdx.x >> 2) * 128;
    int c0t = (blockIdx.x & 3) * 128;
    __shared__ float As[128][33];
    __shared__ float Bs[128][33];
    int t  = threadIdx.x;
    int tr = t >> 4, tc = t & 15;
    float acc[8][8];
#pragma unroll
    for (int i = 0; i < 8; i++)
#pragma unroll
        for (int j = 0; j < 8; j++) acc[i][j] = 0.f;

    for (int kc = 0; kc < 4; kc++) {            // K chunks of 32
        for (int ii = 0; ii < 4; ii++) {
            int idx = t + 256 * ii;             // 0..1023 -> 128 rows x 8 float4
            int r = idx >> 3, c4 = idx & 7;
            {   // A chunk (struct_nodes)
                int grow = b * NP + r0t + r;
                float sc = rnan[grow];
                float f0, f1, f2, f3;
                if (flag) {
                    const unsigned* src = (const unsigned*)anr + ((grow * DIMD + kc * 32 + c4 * 4) >> 1);
                    unsigned w0 = src[0], w1 = src[1];
                    f0 = bf2f_lo(w0); f1 = bf2f_hi(w0); f2 = bf2f_lo(w1); f3 = bf2f_hi(w1);
                } else {
                    float4 v = *((const float4*)((const float*)anr + grow * DIMD + kc * 32 + c4 * 4));
                    f0 = v.x; f1 = v.y; f2 = v.z; f3 = v.w;
                }
                As[r][c4 * 4 + 0] = f0 * sc; As[r][c4 * 4 + 1] = f1 * sc;
                As[r][c4 * 4 + 2] = f2 * sc; As[r][c4 * 4 + 3] = f3 * sc;
            }
            {   // B chunk (seq_tokens)
                int grow = b * NP + c0t + r;
                float sc = rnbn[grow];
                float f0, f1, f2, f3;
                if (flag) {
                    const unsigned* src = (const unsigned*)bnr + ((grow * DIMD + kc * 32 + c4 * 4) >> 1);
                    unsigned w0 = src[0], w1 = src[1];
                    f0 = bf2f_lo(w0); f1 = bf2f_hi(w0); f2 = bf2f_lo(w1); f3 = bf2f_hi(w1);
                } else {
                    float4 v = *((const float4*)((const float*)bnr + grow * DIMD + kc * 32 + c4 * 4));
                    f0 = v.x; f1 = v.y; f2 = v.z; f3 = v.w;
                }
                Bs[r][c4 * 4 + 0] = f0 * sc; Bs[r][c4 * 4 + 1] = f1 * sc;
                Bs[r][c4 * 4 + 2] = f2 * sc; Bs[r][c4 * 4 + 3] = f3 * sc;
            }
        }
        __syncthreads();
        for (int kk = 0; kk < 32; kk++) {
            float av[8], bv[8];
#pragma unroll
            for (int i = 0; i < 8; i++) av[i] = As[tr * 8 + i][kk];
#pragma unroll
            for (int j = 0; j < 8; j++) bv[j] = Bs[tc * 8 + j][kk];
#pragma unroll
            for (int i = 0; i < 8; i++)
#pragma unroll
                for (int j = 0; j < 8; j++) acc[i][j] += av[i] * bv[j];
        }
        __syncthreads();
    }
#pragma unroll
    for (int i = 0; i < 8; i++) {
        int grow = b * NP + r0t + tr * 8 + i;
        unsigned short h[8];
#pragma unroll
        for (int j = 0; j < 8; j++) h[j] = f2bf(expf(acc[i][j] * 10.0f));   // exp(sim/REG)
        uint4 pk;
        pk.x = (unsigned)h[0] | ((unsigned)h[1] << 16);
        pk.y = (unsigned)h[2] | ((unsigned)h[3] << 16);
        pk.z = (unsigned)h[4] | ((unsigned)h[5] << 16);
        pk.w = (unsigned)h[6] | ((unsigned)h[7] << 16);
        *((uint4*)(p0 + ((size_t)grow * NP + c0t + tc * 8))) = pk;
    }
}

// ---------- one Jacobi Sinkhorn step: fused rowsum (P0 v) and col partials (P0^T u) ----------
// grid = 64 examples * 8 rowblocks(64 rows); block = 256 (4 waves, 16 rows/wave).
// Raw sums stored; u=nan_to_num(a/raw) applied at consumption (matches reference exactly).
__global__ void k_iter(const unsigned short* __restrict__ p0, float* __restrict__ rowsum,
                       const float* __restrict__ cp_rd, float* __restrict__ cp_wr, int iter) {
    int b = blockIdx.x >> 3;
    int rb = blockIdx.x & 7;
    int rowbase = rb * 64;
    __shared__ float v_s[512];
    __shared__ float u_s[64];
    __shared__ float colred[4][512];
    int t = threadIdx.x;
    if (iter == 0) {
        for (int j = t; j < 512; j += 256) v_s[j] = MARG;
        if (t < 64) u_s[t] = MARG;
    } else {
        for (int j = t; j < 512; j += 256) {
            float raw = 0.f;
#pragma unroll
            for (int p = 0; p < 8; p++) raw += cp_rd[((b * 8 + p) << 9) + j];
            float q = MARG / raw;
            if (!isfinite(q)) q = MARG;        // nan_to_num(nan/±inf -> 1/n)
            v_s[j] = q;
        }
        if (t < 64) {
            float raw = rowsum[(b << 9) + rowbase + t];
            float q = MARG / raw;
            if (!isfinite(q)) q = MARG;
            u_s[t] = q;
        }
    }
    __syncthreads();
    int w = t >> 6, lane = t & 63;
    float vr[8];
#pragma unroll
    for (int k = 0; k < 8; k++) vr[k] = v_s[lane * 8 + k];
    float ca[8];
#pragma unroll
    for (int k = 0; k < 8; k++) ca[k] = 0.f;
#pragma unroll 4
    for (int r = 0; r < 16; r++) {
        int rl = w * 16 + r;
        int row = rowbase + rl;
        const uint4* src = (const uint4*)(p0 + (((size_t)(b << 9) + row) << 9));
        uint4 pw = src[lane];
        float u_r = u_s[rl];
        float f[8];
        f[0] = bf2f_lo(pw.x); f[1] = bf2f_hi(pw.x);
        f[2] = bf2f_lo(pw.y); f[3] = bf2f_hi(pw.y);
        f[4] = bf2f_lo(pw.z); f[5] = bf2f_hi(pw.z);
        f[6] = bf2f_lo(pw.w); f[7] = bf2f_hi(pw.w);
        float rd = 0.f;
#pragma unroll
        for (int k = 0; k < 8; k++) { rd += f[k] * vr[k]; ca[k] += f[k] * u_r; }
        rd = wred64(rd);
        if (lane == 0) rowsum[(b << 9) + row] = rd;   // raw sum; divide at consumption
    }
#pragma unroll
    for (int k = 0; k < 8; k++) colred[w][lane * 8 + k] = ca[k];
    __syncthreads();
    for (int j = t; j < 512; j += 256) {
        float s = colred[0][j] + colred[1][j] + colred[2][j] + colred[3][j];
        cp_wr[((b * 8 + rb) << 9) + j] = s;
    }
}

// ---------- final: P = u P0 v ; loss += P * (-0.1*log(P0)); adds local/B into outf[1], outf[2] ----------
__global__ void k_final(const unsigned short* __restrict__ p0, const float* __restrict__ rowsum,
                        const float* __restrict__ cp_rd, float* outf) {
    int b = blockIdx.x >> 3;
    int rb = blockIdx.x & 7;
    int rowbase = rb * 64;
    __shared__ float v_s[512];
    __shared__ float u_s[64];
    __shared__ float bs[4];
    int t = threadIdx.x;
    for (int j = t; j < 512; j += 256) {
        float raw = 0.f;
#pragma unroll
        for (int p = 0; p < 8; p++) raw += cp_rd[((b * 8 + p) << 9) + j];
        float q = MARG / raw;
        if (!isfinite(q)) q = MARG;
        v_s[j] = q;
    }
    if (t < 64) {
        float raw = rowsum[(b << 9) + rowbase + t];
        float q = MARG / raw;
        if (!isfinite(q)) q = MARG;
        u_s[t] = q;
    }
    __syncthreads();
    int w = t >> 6, lane = t & 63;
    float vr[8];
#pragma unroll
    for (int k = 0; k < 8; k++) vr[k] = v_s[lane * 8 + k];
    float acc = 0.f;
    for (int r = 0; r < 16; r++) {
        int rl = w * 16 + r;
        int row = rowbase + rl;
        const uint4* src = (const uint4*)(p0 + (((size_t)(b << 9) + row) << 9));
        uint4 pw = src[lane];
        float u_r = u_s[rl];
        float f[8];
        f[0] = bf2f_lo(pw.x); f[1] = bf2f_hi(pw.x);
        f[2] = bf2f_lo(pw.y); f[3] = bf2f_hi(pw.y);
        f[4] = bf2f_lo(pw.z); f[5] = bf2f_hi(pw.z);
        f[6] = bf2f_lo(pw.w); f[7] = bf2f_hi(pw.w);
#pragma unroll
        for (int k = 0; k < 8; k++) {
            float p = f[k];
            acc += u_r * p * vr[k] * (-0.1f) * logf(p);   // C = -log(P0)/10
        }
    }
    acc = wred64(acc);
    if (lane == 0) bs[w] = acc;
    __syncthreads();
    if (t == 0) {
        float c = (bs[0] + bs[1] + bs[2] + bs[3]) * (1.0f / 64.0f);   // /B
        atomicAdd(&outf[1], c);
        atomicAdd(&outf[2], c);
    }
}

extern "C" void kernel_launch(void* const* d_in, const int* in_sizes, int n_in,
                              void* d_out, int out_size, void* d_ws, size_t ws_size,
                              hipStream_t stream) {
    const void* sg = d_in[0];
    const void* qg = d_in[1];
    const void* an = d_in[2];
    const void* bn = d_in[3];
    char* ws = (char*)d_ws;
    float* outf = (float*)d_out;                     // reference output dtype: float32 x3

    int*   flagp   = (int*)ws;
    float* simg    = (float*)(ws + O_SIMG);
    float* rnsg    = (float*)(ws + O_RNSG);
    float* rnqg    = (float*)(ws + O_RNQG);
    float* rnan    = (float*)(ws + O_RNAN);
    float* rnbn    = (float*)(ws + O_RNBN);
    float* rowsum  = (float*)(ws + O_ROWSUM);
    float* colp    = (float*)(ws + O_COLP);          // 2 banks
    unsigned short* p0 = (unsigned short*)(ws + O_P0);

    k_detect<<<1, 256, 0, stream>>>((const unsigned*)sg, flagp, outf);
    k_rnorm<<<16, 256, 0, stream>>>(sg, rnsg, 64, flagp);
    k_rnorm<<<16, 256, 0, stream>>>(qg, rnqg, 64, flagp);
    k_rnorm<<<8192, 256, 0, stream>>>(an, rnan, 32768, flagp);
    k_rnorm<<<8192, 256, 0, stream>>>(bn, rnbn, 32768, flagp);
    k_simg<<<16, 256, 0, stream>>>(sg, qg, rnsg, rnqg, simg, flagp);
    k_gloss<<<1, 256, 0, stream>>>(simg, outf);
    k_build<<<dim3(16, 64), 256, 0, stream>>>(an, bn, rnan, rnbn, p0, flagp);

    float* cp0 = colp;
    float* cp1 = colp + COLP_BANK;
    for (int it = 0; it < NITER; ++it) {
        float* wr = (it & 1) ? cp1 : cp0;
        float* rd = (it & 1) ? cp0 : cp1;            // unused when it==0
        k_iter<<<512, 256, 0, stream>>>(p0, rowsum, rd, wr, it);
    }
    // last iter (99, odd) wrote cp1
    k_final<<<512, 256, 0, stream>>>(p0, rowsum, cp1, outf);
}